// Round 11
// baseline (224.540 us; speedup 1.0000x reference)
//
#include <hip/hip_runtime.h>

#define SBD   384
#define NCATS 64
#define EMB   48
#define HT    256
#define HC    128

typedef __attribute__((ext_vector_type(8))) short short8;
typedef __attribute__((ext_vector_type(4))) float f32x4;

__device__ __forceinline__ short f2bf(float x) {
    union { float f; unsigned u; } v; v.f = x;
    unsigned r = v.u + 0x7FFF + ((v.u >> 16) & 1);   // RNE
    return (short)(r >> 16);
}

__device__ __forceinline__ short8 cvt8(float4 a, float4 b) {
    short8 h;
    h[0] = f2bf(a.x); h[1] = f2bf(a.y); h[2] = f2bf(a.z); h[3] = f2bf(a.w);
    h[4] = f2bf(b.x); h[5] = f2bf(b.y); h[6] = f2bf(b.z); h[7] = f2bf(b.w);
    return h;
}

__device__ __forceinline__ void glds16(const void* g, void* l) {
    __builtin_amdgcn_global_load_lds((const __attribute__((address_space(1))) void*)g,
                                     (__attribute__((address_space(3))) void*)l, 16, 0, 0);
}

#define MFMA(a, b, c) __builtin_amdgcn_mfma_f32_16x16x32_bf16((a), (b), (c), 0, 0, 0)

// ---------------------------------------------------------------------------
// Prep.
// iT1: 12 chunks of [256n][32k] bf16 (16KB each), rows (64B) pre-swizzled
//      byte ^= (n&7)<<4  -- glds'd linearly into the encoder's B dbuf.
// iK2: LINEAR [n][k] bf16 frag images read per-frag from global in the tail:
//      iT2 [48][256] @0 (24KB) | iC1 [128][64] @24576 | iC2 [48][128] @40960.
// ---------------------------------------------------------------------------
__global__ void prep_weights(const float* __restrict__ Wt1, const float* __restrict__ Wt2,
                             const float* __restrict__ Wc1, const float* __restrict__ Wc2,
                             char* __restrict__ iT1, char* __restrict__ iK2) {
    int t = blockIdx.x * blockDim.x + threadIdx.x;
    int stride = gridDim.x * blockDim.x;
    for (int g = t; g < 256 * 48; g += stride) {       // Wt1 [384k][256n]
        int n = g / 48, k0 = (g - n * 48) * 8;
        int c = k0 >> 5, kin = k0 & 31;
        short8 v;
        #pragma unroll
        for (int j = 0; j < 8; ++j) v[j] = f2bf(Wt1[(size_t)(k0 + j) * HT + n]);
        *(short8*)(iT1 + (size_t)c * 16384 + ((n * 64 + kin * 2) ^ ((n & 7) << 4))) = v;
    }
    for (int g = t; g < 48 * 32; g += stride) {        // Wt2 [256k][48n]
        int n = g / 32, k0 = (g - n * 32) * 8;
        short8 v;
        #pragma unroll
        for (int j = 0; j < 8; ++j) v[j] = f2bf(Wt2[(size_t)(k0 + j) * EMB + n]);
        *(short8*)(iK2 + n * 512 + k0 * 2) = v;
    }
    for (int g = t; g < 128 * 8; g += stride) {        // Wc1 [64k][128n]
        int n = g / 8, k0 = (g - n * 8) * 8;
        short8 v;
        #pragma unroll
        for (int j = 0; j < 8; ++j) v[j] = f2bf(Wc1[(size_t)(k0 + j) * HC + n]);
        *(short8*)(iK2 + 24576 + n * 128 + k0 * 2) = v;
    }
    for (int g = t; g < 48 * 16; g += stride) {        // Wc2 [128k][48n]
        int n = g / 16, k0 = (g - n * 16) * 8;
        short8 v;
        #pragma unroll
        for (int j = 0; j < 8; ++j) v[j] = f2bf(Wc2[(size_t)(k0 + j) * EMB + n]);
        *(short8*)(iK2 + 40960 + n * 256 + k0 * 2) = v;
    }
}

// ---------------------------------------------------------------------------
// Fused encoder v11: 64 books/block, 1563 blocks, 256 thr (4 waves, 1m x 4n;
// wave tile 64 rows x 64 cols).  LDS exactly 80KB -> 2 blocks/CU: the key
// change vs R10 (148KB, 1 block/CU).  Two independent barrier domains per CU
// overlap each other's drains/stages.
//   L1  : A bf16 [64][384] swz @0 (48K) ; B dbuf 2x16K @49152
//   tail: H1t [64][256] swz @0 (32K, dead A) ; H1c 4x4K @49152 (dead B);
//         tail B-frags straight from global linear iK2 (L2-resident).
// Main loop NOT unrolled (compact code; LDS offsets runtime, reg arrays static).
// ---------------------------------------------------------------------------
__global__ __launch_bounds__(256, 2) void encode_fused(
    const float* __restrict__ sbert, const float* __restrict__ mh,
    const char* __restrict__ iT1, const char* __restrict__ iK2,
    const float* __restrict__ bt1, const float* __restrict__ bt2,
    const float* __restrict__ bc1, const float* __restrict__ bc2,
    float* __restrict__ E, int nbooks)
{
    __shared__ char lds[81920];

    const int t  = threadIdx.x;
    const int w  = t >> 6;
    const int l  = t & 63;
    const int lr = l & 15;
    const int lg = l >> 4;
    const int book0 = (int)blockIdx.x * 64;
    const int sw = (lr & 7) << 4;

    // ---- tail mh loads early (hidden under L1) ----
    float4 mf0, mf1, mf2, mf3;
    {
        const float* mp = mh + (size_t)min(book0 + w * 16 + lr, nbooks - 1) * NCATS + lg * 8;
        mf0 = *(const float4*)(mp);      mf1 = *(const float4*)(mp + 4);
        mf2 = *(const float4*)(mp + 32); mf3 = *(const float4*)(mp + 36);
    }

    // ---- A-stage: 64x384 fp32 -> bf16 swz LDS @0 (12 granules/thread) ----
    #pragma unroll
    for (int j = 0; j < 12; ++j) {
        int G = t + 256 * j;
        int row = G / 48, c8 = G - row * 48;
        const float* p = sbert + (size_t)min(book0 + row, nbooks - 1) * SBD + c8 * 8;
        float4 a = *(const float4*)p, b = *(const float4*)(p + 4);
        *(short8*)(lds + ((row * 768 + c8 * 16) ^ ((row & 7) << 4))) = cvt8(a, b);
    }
    // ---- B chunk 0 (16KB, 4 glds/thread) ----
    #pragma unroll
    for (int j = 0; j < 4; ++j)
        glds16(iT1 + t * 16 + j * 4096, lds + 49152 + t * 16 + j * 4096);
    __syncthreads();

    // ---- L1: 12 chunks, dbuf ----
    f32x4 acc[4][4];
    #pragma unroll
    for (int bi = 0; bi < 4; ++bi) {
        float b = bt1[w * 64 + bi * 16 + lr];
        #pragma unroll
        for (int ai = 0; ai < 4; ++ai) acc[ai][bi] = (f32x4){b, b, b, b};
    }

    for (int c = 0; c < 12; ++c) {
        const int boff = 49152 + (c & 1) * 16384;
        const int noff = 49152 + ((c & 1) ^ 1) * 16384;
        if (c < 11) {
            #pragma unroll
            for (int j = 0; j < 4; ++j)
                glds16(iT1 + (size_t)(c + 1) * 16384 + t * 16 + j * 4096,
                       lds + noff + t * 16 + j * 4096);
        }
        short8 Af[4], Bf[4];
        #pragma unroll
        for (int ai = 0; ai < 4; ++ai)
            Af[ai] = *(const short8*)(lds +
                (((ai * 16 + lr) * 768 + (c * 32 + lg * 8) * 2) ^ sw));
        #pragma unroll
        for (int bi = 0; bi < 4; ++bi)
            Bf[bi] = *(const short8*)(lds + boff +
                (((w * 64 + bi * 16 + lr) * 64 + lg * 16) ^ sw));
        #pragma unroll
        for (int ai = 0; ai < 4; ++ai)
            #pragma unroll
            for (int bi = 0; bi < 4; ++bi)
                acc[ai][bi] = MFMA(Af[ai], Bf[bi], acc[ai][bi]);
        asm volatile("s_waitcnt vmcnt(0) lgkmcnt(0)" ::: "memory");
        __builtin_amdgcn_sched_barrier(0);
        __builtin_amdgcn_s_barrier();
    }

    // ---- H1t relu->bf16 -> LDS @0 [64][256] swz (dead A region) ----
    #pragma unroll
    for (int ai = 0; ai < 4; ++ai)
        #pragma unroll
        for (int bi = 0; bi < 4; ++bi)
            #pragma unroll
            for (int r = 0; r < 4; ++r) {
                int row = ai * 16 + lg * 4 + r;
                int col = w * 64 + bi * 16 + lr;
                *(unsigned short*)(lds + ((row * 512 + col * 2) ^ ((row & 7) << 4))) =
                    (unsigned short)f2bf(fmaxf(acc[ai][bi][r], 0.f));
            }
    asm volatile("s_waitcnt lgkmcnt(0)" ::: "memory");
    __builtin_amdgcn_sched_barrier(0);
    __builtin_amdgcn_s_barrier();

    // ================= tail: wave w owns books book0+16w..+16 =================
    char* hc = lds + 49152 + w * 4096;   // dead B region, wave-private

    // L2 txt: A = H1t rows w*16+lr (LDS); B from global iT2 linear
    f32x4 acct[3];
    #pragma unroll
    for (int nt = 0; nt < 3; ++nt) { float b = bt2[nt * 16 + lr]; acct[nt] = (f32x4){b, b, b, b}; }
    #pragma unroll
    for (int ks = 0; ks < 8; ++ks) {
        short8 af = *(const short8*)(lds +
            (((w * 16 + lr) * 512 + (ks * 32 + lg * 8) * 2) ^ sw));
        #pragma unroll
        for (int nt = 0; nt < 3; ++nt) {
            short8 bf = *(const short8*)(iK2 + (nt * 16 + lr) * 512 + (ks * 32 + lg * 8) * 2);
            acct[nt] = MFMA(af, bf, acct[nt]);
        }
    }

    // cat L1: mh regs @ Wc1 (global linear), K=64
    short8 c0 = cvt8(mf0, mf1), c1 = cvt8(mf2, mf3);
    f32x4 accc[8];
    #pragma unroll
    for (int nt = 0; nt < 8; ++nt) { float b = bc1[nt * 16 + lr]; accc[nt] = (f32x4){b, b, b, b}; }
    #pragma unroll
    for (int nt = 0; nt < 8; ++nt) {
        short8 b0 = *(const short8*)(iK2 + 24576 + (nt * 16 + lr) * 128 + lg * 16);
        short8 b1 = *(const short8*)(iK2 + 24576 + (nt * 16 + lr) * 128 + 64 + lg * 16);
        accc[nt] = MFMA(c0, b0, accc[nt]);
        accc[nt] = MFMA(c1, b1, accc[nt]);
    }

    // H1c (wave-private LDS, lgkm only)
    #pragma unroll
    for (int nt = 0; nt < 8; ++nt)
        #pragma unroll
        for (int r = 0; r < 4; ++r) {
            int rr = lg * 4 + r;
            *(unsigned short*)(hc + ((rr * 256 + (nt * 16 + lr) * 2) ^ ((rr & 7) << 4))) =
                (unsigned short)f2bf(fmaxf(accc[nt][r], 0.f));
        }
    asm volatile("s_waitcnt lgkmcnt(0)" ::: "memory");
    __builtin_amdgcn_sched_barrier(0);

    // cat L2: K=128; B from global iC2 linear
    f32x4 acc2[3];
    #pragma unroll
    for (int nt = 0; nt < 3; ++nt) { float b = bc2[nt * 16 + lr]; acc2[nt] = (f32x4){b, b, b, b}; }
    #pragma unroll
    for (int ks = 0; ks < 4; ++ks) {
        short8 af = *(const short8*)(hc + ((lr * 256 + (ks * 32 + lg * 8) * 2) ^ sw));
        #pragma unroll
        for (int nt = 0; nt < 3; ++nt) {
            short8 bf = *(const short8*)(iK2 + 40960 + (nt * 16 + lr) * 256 + (ks * 32 + lg * 8) * 2);
            acc2[nt] = MFMA(af, bf, acc2[nt]);
        }
    }

    // combine, l2norm, store E
    f32x4 comb[3];
    #pragma unroll
    for (int nt = 0; nt < 3; ++nt)
        #pragma unroll
        for (int r = 0; r < 4; ++r) comb[nt][r] = 3.0f * acc2[nt][r] + acct[nt][r];
    #pragma unroll
    for (int r = 0; r < 4; ++r) {
        float ss = comb[0][r] * comb[0][r] + comb[1][r] * comb[1][r] + comb[2][r] * comb[2][r];
        ss += __shfl_xor(ss, 1); ss += __shfl_xor(ss, 2);
        ss += __shfl_xor(ss, 4); ss += __shfl_xor(ss, 8);
        float rn = rsqrtf(fmaxf(ss, 1e-12f));
        int grow = book0 + w * 16 + lg * 4 + r;
        if (grow < nbooks) {
            #pragma unroll
            for (int nt = 0; nt < 3; ++nt)
                E[(size_t)grow * EMB + nt * 16 + lr] = comb[nt][r] * rn;
        }
    }
}

// ---------------------------------------------------------------------------
// Scoring: 16 lanes/sample, 3 dims/lane, shuffle-reduce.
// ---------------------------------------------------------------------------
__global__ __launch_bounds__(256) void score_kernel(
    const int* __restrict__ user_idx, const int* __restrict__ loc_idx,
    const int* __restrict__ pos_idx,  const int* __restrict__ neg_idx,
    const float* __restrict__ ucat, const float* __restrict__ utxt,
    const float* __restrict__ lcat, const float* __restrict__ ltxt,
    const float* __restrict__ E, float* __restrict__ out, int Bn)
{
    const int t    = threadIdx.x;
    const int lane = t & 15;
    const int s    = blockIdx.x * 16 + (t >> 4);
    if (s >= Bn) return;

    const int ui = user_idx[s];
    const int li = loc_idx[s];
    const int pi = pos_idx[s];
    const int ni = neg_idx[s];

    const int d0 = lane * 3;
    const float* uc = ucat + (size_t)ui * EMB + d0;
    const float* ut = utxt + (size_t)ui * EMB + d0;
    const float* lc = lcat + (size_t)li * EMB + d0;
    const float* lt = ltxt + (size_t)li * EMB + d0;
    const float* pp = E + (size_t)pi * EMB + d0;
    const float* nn = E + (size_t)ni * EMB + d0;

    float u0 = 3.0f * (uc[0] + lc[0]) + (ut[0] + lt[0]);
    float u1 = 3.0f * (uc[1] + lc[1]) + (ut[1] + lt[1]);
    float u2 = 3.0f * (uc[2] + lc[2]) + (ut[2] + lt[2]);

    float usq = u0 * u0 + u1 * u1 + u2 * u2;
    float ps  = u0 * pp[0] + u1 * pp[1] + u2 * pp[2];
    float ns  = u0 * nn[0] + u1 * nn[1] + u2 * nn[2];

    #pragma unroll
    for (int m = 1; m < 16; m <<= 1) {
        usq += __shfl_xor(usq, m);
        ps  += __shfl_xor(ps, m);
        ns  += __shfl_xor(ns, m);
    }

    if (lane == 0) {
        const float inv = rsqrtf(fmaxf(usq, 1e-12f)) * 20.0f;  // /TEMP
        out[2 * (size_t)s + 0] = ps * inv;
        out[2 * (size_t)s + 1] = ns * inv;
    }
}

extern "C" void kernel_launch(void* const* d_in, const int* in_sizes, int n_in,
                              void* d_out, int out_size, void* d_ws, size_t ws_size,
                              hipStream_t stream) {
    const int*   user_idx = (const int*)d_in[0];
    const int*   loc_idx  = (const int*)d_in[1];
    const int*   pos_idx  = (const int*)d_in[2];
    const int*   neg_idx  = (const int*)d_in[3];
    const float* ucat     = (const float*)d_in[4];
    const float* utxt     = (const float*)d_in[5];
    const float* lcat     = (const float*)d_in[6];
    const float* ltxt     = (const float*)d_in[7];
    const float* sbert    = (const float*)d_in[8];
    const float* mh       = (const float*)d_in[9];
    const float* Wc1      = (const float*)d_in[10];
    const float* bc1      = (const float*)d_in[11];
    const float* Wc2      = (const float*)d_in[12];
    const float* bc2      = (const float*)d_in[13];
    const float* Wt1      = (const float*)d_in[14];
    const float* bt1      = (const float*)d_in[15];
    const float* Wt2      = (const float*)d_in[16];
    const float* bt2      = (const float*)d_in[17];

    const int Bn     = in_sizes[0];
    const int nbooks = in_sizes[8] / SBD;          // 100000

    char* ws = (char*)d_ws;
    float* E = (float*)ws;
    size_t off = ((size_t)nbooks * EMB * 4 + 255) & ~(size_t)255;
    char* iT1 = ws + off;  off += 196608;
    char* iK2 = ws + off;  off += 53248;

    hipLaunchKernelGGL(prep_weights, dim3(64), dim3(256), 0, stream,
                       Wt1, Wt2, Wc1, Wc2, iT1, iK2);

    const int nblocks = (nbooks + 63) / 64;        // 1563
    hipLaunchKernelGGL(encode_fused, dim3(nblocks), dim3(256), 0, stream,
                       sbert, mh, iT1, iK2, bt1, bt2, bc1, bc2, E, nbooks);

    const int nblocksB = (Bn + 15) / 16;
    hipLaunchKernelGGL(score_kernel, dim3(nblocksB), dim3(256), 0, stream,
                       user_idx, loc_idx, pos_idx, neg_idx,
                       ucat, utxt, lcat, ltxt, E, (float*)d_out, Bn);
}